// Round 4
// baseline (1451.704 us; speedup 1.0000x reference)
//
#include <hip/hip_runtime.h>
#include <cstdint>
#include <cstddef>

#define RANGE   128        // nodes per bucket
#define RSHIFT  7
#define MAXBUCK 800        // >= ceil(N/RANGE); N=100K -> 782
#define CH      4096       // edges per partition block (small => high occupancy)
#define PAD     16         // pad global counters to one 64B line each

// ---------------------------------------------------------------------------
__global__ void zero_pad_kernel(int* __restrict__ p, int n) {
    int i = blockIdx.x * blockDim.x + threadIdx.x;
    if (i < n) p[i * PAD] = 0;
}

// per-block LDS histogram of col>>7, merged with ~nbuck global atomics/block
__global__ void count_kernel(const int* __restrict__ col, int* __restrict__ bcnt,
                             int nbuck, int E) {
    __shared__ int lcnt[MAXBUCK];
    int tid = threadIdx.x;
    for (int i = tid; i < nbuck; i += blockDim.x) lcnt[i] = 0;
    __syncthreads();
    int base = blockIdx.x * CH;
    int end  = min(E, base + CH);
    for (int e = base + tid; e < end; e += blockDim.x)
        atomicAdd(&lcnt[col[e] >> RSHIFT], 1);
    __syncthreads();
    for (int i = tid; i < nbuck; i += blockDim.x)
        if (lcnt[i]) atomicAdd(&bcnt[i * PAD], lcnt[i]);
}

// exclusive scan of bucket counts (nbuck <= 1024), init padded cursors
__global__ void scan_buckets_kernel(const int* __restrict__ bcnt, int* __restrict__ bbase,
                                    int* __restrict__ cursor, int nbuck, int E) {
    __shared__ int lds[1024];
    int T = threadIdx.x;
    int s = (T < nbuck) ? bcnt[T * PAD] : 0;
    lds[T] = s;
    __syncthreads();
    for (int off = 1; off < 1024; off <<= 1) {
        int v = (T >= off) ? lds[T - off] : 0;
        __syncthreads();
        lds[T] += v;
        __syncthreads();
    }
    int excl = lds[T] - s;
    if (T < nbuck) { bbase[T] = excl; cursor[T * PAD] = excl; }
    if (T == 0)    bbase[nbuck] = E;
}

// scatter edges into bucket-grouped records; per-edge offsets via LDS cursors,
// ~nbuck global atomics per block.  record = {row | dst_local<<17, ew}
__global__ void scatter_kernel(const int* __restrict__ row, const int* __restrict__ col,
                               const float* __restrict__ ew, int* __restrict__ cursor,
                               uint2* __restrict__ part, int nbuck, int E) {
    __shared__ int lcnt[MAXBUCK];
    __shared__ int lbase[MAXBUCK];
    int tid = threadIdx.x;
    for (int i = tid; i < nbuck; i += blockDim.x) lcnt[i] = 0;
    __syncthreads();
    int base = blockIdx.x * CH;
    int end  = min(E, base + CH);
    for (int e = base + tid; e < end; e += blockDim.x)
        atomicAdd(&lcnt[col[e] >> RSHIFT], 1);
    __syncthreads();
    for (int i = tid; i < nbuck; i += blockDim.x) {
        int c = lcnt[i];
        lbase[i] = c ? atomicAdd(&cursor[i * PAD], c) : 0;
        lcnt[i] = 0;
    }
    __syncthreads();
    for (int e = base + tid; e < end; e += blockDim.x) {
        int c = col[e];
        int b = c >> RSHIFT;
        int off = atomicAdd(&lcnt[b], 1);
        part[lbase[b] + off] =
            make_uint2((unsigned)row[e] | ((unsigned)(c & (RANGE - 1)) << 17),
                       __float_as_uint(ew[e]));
    }
}

// one block per bucket: dis[node] = rsqrt(1 + sum ew into node), via LDS f32 atomics
__global__ void deg_dis_kernel(const uint2* __restrict__ part, const int* __restrict__ bbase,
                               float* __restrict__ dis, int N) {
    __shared__ float sdeg[RANGE];
    int b = blockIdx.x;
    int tid = threadIdx.x;
    int s = bbase[b], t = bbase[b + 1];
    if (tid < RANGE) sdeg[tid] = 1.0f;  // self-loop weight
    __syncthreads();
    for (int e = s + tid; e < t; e += blockDim.x) {
        uint2 r = part[e];
        atomicAdd(&sdeg[(r.x >> 17) & (RANGE - 1)], __uint_as_float(r.y));
    }
    __syncthreads();
    int node = b * RANGE + tid;
    if (tid < RANGE && node < N) dis[node] = rsqrtf(sdeg[tid]);
}

// t1 = X @ W1   ([N,128] @ [128,12], stride 16); one wave per node
__global__ void lin1_kernel(const float* __restrict__ X, const float* __restrict__ W1,
                            float* __restrict__ t1, int n) {
    int node = (int)((blockIdx.x * (size_t)blockDim.x + threadIdx.x) >> 6);
    int lane = threadIdx.x & 63;
    if (node >= n) return;
    const float* xr = X + (size_t)node * 128;
    float x0 = xr[lane];
    float x1 = xr[lane + 64];
    float res[12];
#pragma unroll
    for (int o = 0; o < 12; o++) {
        float p = x0 * W1[lane * 12 + o] + x1 * W1[(lane + 64) * 12 + o];
#pragma unroll
        for (int off = 32; off > 0; off >>= 1) p += __shfl_xor(p, off, 64);
        res[o] = p;
    }
    if (lane == 0) {
        float4* o4 = (float4*)(t1 + (size_t)node * 16);
        o4[0] = make_float4(res[0], res[1], res[2], res[3]);
        o4[1] = make_float4(res[4], res[5], res[6], res[7]);
        o4[2] = make_float4(res[8], res[9], res[10], res[11]);
    }
}

// Bucket-level aggregation straight from `part`: one block per 128-node bucket.
// LDS accumulator tile [RANGE][ASTR] (odd stride -> conflict-light ds_add_f32),
// coalesced streaming read of the bucket's edges, per-edge gather of hin[src].
//   FIRST: norm = dis[dst]*ew*dis[src], written back into part[e].y
//   epilogue: v = relu(acc + dis^2*hin[node] + b_this); matvec W_next (or sigmoid)
template <int DIN, int SIN, int DOUT, int SOUT, bool FIRST, bool LAST>
__global__ void agg_kernel(const int* __restrict__ bbase, uint2* __restrict__ part,
                           const float* __restrict__ dis, const float* __restrict__ hin,
                           const float* __restrict__ b_this, const float* __restrict__ W_next,
                           const float* __restrict__ b_next, float* __restrict__ hout, int N) {
    constexpr int ASTR = DIN | 1;          // 12->13, 6->7, 3->3 (gcd(.,32)=1)
    __shared__ float acc[RANGE * ASTR];
    __shared__ float sdis[RANGE];
    int b   = blockIdx.x;
    int tid = threadIdx.x;
    int s = bbase[b], t = bbase[b + 1];
    for (int i = tid; i < RANGE * ASTR; i += blockDim.x) acc[i] = 0.f;
    if (tid < RANGE) {
        int node = b * RANGE + tid;
        sdis[tid] = (node < N) ? dis[node] : 0.f;
    }
    __syncthreads();

    for (int e = s + tid; e < t; e += blockDim.x) {
        uint2 ev = part[e];
        int src = (int)(ev.x & 0x1FFFFu);
        int c   = (int)((ev.x >> 17) & (RANGE - 1));
        float norm;
        if constexpr (FIRST) {
            norm = sdis[c] * __uint_as_float(ev.y) * dis[src];
            part[e].y = __float_as_uint(norm);
        } else {
            norm = __uint_as_float(ev.y);
        }
        const float* hr = hin + (size_t)src * SIN;
        float* a = acc + c * ASTR;
        if constexpr (DIN == 12) {
            const float4* p = (const float4*)hr;
            float4 h0 = p[0], h1 = p[1], h2 = p[2];
            atomicAdd(a + 0,  norm * h0.x);  atomicAdd(a + 1,  norm * h0.y);
            atomicAdd(a + 2,  norm * h0.z);  atomicAdd(a + 3,  norm * h0.w);
            atomicAdd(a + 4,  norm * h1.x);  atomicAdd(a + 5,  norm * h1.y);
            atomicAdd(a + 6,  norm * h1.z);  atomicAdd(a + 7,  norm * h1.w);
            atomicAdd(a + 8,  norm * h2.x);  atomicAdd(a + 9,  norm * h2.y);
            atomicAdd(a + 10, norm * h2.z);  atomicAdd(a + 11, norm * h2.w);
        } else if constexpr (DIN == 6) {
            float4 h0 = *(const float4*)hr;
            float2 h1 = *(const float2*)(hr + 4);
            atomicAdd(a + 0, norm * h0.x);  atomicAdd(a + 1, norm * h0.y);
            atomicAdd(a + 2, norm * h0.z);  atomicAdd(a + 3, norm * h0.w);
            atomicAdd(a + 4, norm * h1.x);  atomicAdd(a + 5, norm * h1.y);
        } else {  // DIN == 3
            float4 h0 = *(const float4*)hr;
            atomicAdd(a + 0, norm * h0.x);  atomicAdd(a + 1, norm * h0.y);
            atomicAdd(a + 2, norm * h0.z);
        }
    }
    __syncthreads();

    if (tid < RANGE) {
        int node = b * RANGE + tid;
        if (node < N) {
            float dn = sdis[tid];
            float s2 = dn * dn;
            const float* hn = hin + (size_t)node * SIN;
            const float* a  = acc + tid * ASTR;
            float v[DIN];
#pragma unroll
            for (int d = 0; d < DIN; d++)
                v[d] = fmaxf(a[d] + s2 * hn[d] + b_this[d], 0.f);
            if constexpr (!LAST) {
                float o[DOUT];
#pragma unroll
                for (int oo = 0; oo < DOUT; oo++) {
                    float z = 0.f;
#pragma unroll
                    for (int d = 0; d < DIN; d++) z += v[d] * W_next[d * DOUT + oo];
                    o[oo] = z;
                }
                float* op = hout + (size_t)node * SOUT;
                if constexpr (DOUT == 6) {
                    *(float4*)op       = make_float4(o[0], o[1], o[2], o[3]);
                    *(float4*)(op + 4) = make_float4(o[4], o[5], 0.f, 0.f);
                } else {  // DOUT == 3, SOUT == 4
                    *(float4*)op = make_float4(o[0], o[1], o[2], 0.f);
                }
            } else {
                float z = b_next[0];
#pragma unroll
                for (int d = 0; d < DIN; d++) z += v[d] * W_next[d];
                hout[node] = 1.0f / (1.0f + expf(-z));
            }
        }
    }
}

// ---------------------------------------------------------------------------
extern "C" void kernel_launch(void* const* d_in, const int* in_sizes, int n_in,
                              void* d_out, int out_size, void* d_ws, size_t ws_size,
                              hipStream_t stream) {
    const float* X  = (const float*)d_in[0];
    const int*   ei = (const int*)d_in[1];
    const float* ew = (const float*)d_in[2];
    const float* W1 = (const float*)d_in[3];
    const float* b1 = (const float*)d_in[4];
    const float* W2 = (const float*)d_in[5];
    const float* b2 = (const float*)d_in[6];
    const float* W3 = (const float*)d_in[7];
    const float* b3 = (const float*)d_in[8];
    const float* Wl = (const float*)d_in[9];
    const float* bl = (const float*)d_in[10];
    float* out = (float*)d_out;

    const int N = in_sizes[0] / 128;
    const int E = in_sizes[1] / 2;
    const int* row = ei;
    const int* col = ei + E;
    const int nbuck = (N + RANGE - 1) >> RSHIFT;

    char* ws = (char*)d_ws;
    size_t off = 0;
    auto carve = [&](size_t bytes) -> void* {
        void* p = ws + off;
        off += (bytes + 255) & ~(size_t)255;
        return p;
    };
    int*   bcnt   = (int*)  carve((size_t)MAXBUCK * PAD * 4);
    int*   cursor = (int*)  carve((size_t)MAXBUCK * PAD * 4);
    int*   bbase  = (int*)  carve((size_t)(MAXBUCK + 1) * 4);
    float* dis    = (float*)carve((size_t)N * 4);
    uint2* part   = (uint2*)carve((size_t)E * 8);
    float* t1     = (float*)carve((size_t)N * 16 * 4);
    float* t2     = (float*)carve((size_t)N * 8 * 4);
    float* t3     = (float*)carve((size_t)N * 4 * 4);
    (void)ws_size; (void)n_in; (void)out_size;

    const int bP = (E + CH - 1) / CH;   // 1563 partition blocks
    const int bW = (N + 3) / 4;         // lin1: wave per node

    zero_pad_kernel<<<(nbuck + 255) / 256, 256, 0, stream>>>(bcnt, nbuck);
    count_kernel<<<bP, 256, 0, stream>>>(col, bcnt, nbuck, E);
    scan_buckets_kernel<<<1, 1024, 0, stream>>>(bcnt, bbase, cursor, nbuck, E);
    scatter_kernel<<<bP, 256, 0, stream>>>(row, col, ew, cursor, part, nbuck, E);
    deg_dis_kernel<<<nbuck, 256, 0, stream>>>(part, bbase, dis, N);
    lin1_kernel<<<bW, 256, 0, stream>>>(X, W1, t1, N);
    agg_kernel<12, 16, 6, 8, true,  false><<<nbuck, 256, 0, stream>>>(bbase, part, dis, t1, b1, W2, nullptr, t2, N);
    agg_kernel< 6,  8, 3, 4, false, false><<<nbuck, 256, 0, stream>>>(bbase, part, dis, t2, b2, W3, nullptr, t3, N);
    agg_kernel< 3,  4, 1, 1, false, true ><<<nbuck, 256, 0, stream>>>(bbase, part, dis, t3, b3, Wl, bl, out, N);
}

// Round 5
// 782.633 us; speedup vs baseline: 1.8549x; 1.8549x over previous
//
#include <hip/hip_runtime.h>
#include <cstdint>
#include <cstddef>

#define RANGE   128        // nodes per bucket
#define RSHIFT  7
#define MAXBUCK 800        // >= ceil(N/RANGE); N=100K -> 782
#define CH      4096       // edges per partition block (small => high occupancy)
#define PAD     16         // pad global counters to one 64B line each

// ---------------------------------------------------------------------------
__global__ void zero_pad_kernel(int* __restrict__ p, int n) {
    int i = blockIdx.x * blockDim.x + threadIdx.x;
    if (i < n) p[i * PAD] = 0;
}

// per-block LDS histogram of col>>7, merged with ~nbuck global atomics/block
__global__ void count_kernel(const int* __restrict__ col, int* __restrict__ bcnt,
                             int nbuck, int E) {
    __shared__ int lcnt[MAXBUCK];
    int tid = threadIdx.x;
    for (int i = tid; i < nbuck; i += blockDim.x) lcnt[i] = 0;
    __syncthreads();
    int base = blockIdx.x * CH;
    int end  = min(E, base + CH);
    for (int e = base + tid; e < end; e += blockDim.x)
        atomicAdd(&lcnt[col[e] >> RSHIFT], 1);
    __syncthreads();
    for (int i = tid; i < nbuck; i += blockDim.x)
        if (lcnt[i]) atomicAdd(&bcnt[i * PAD], lcnt[i]);
}

// exclusive scan of bucket counts (nbuck <= 1024), init padded cursors
__global__ void scan_buckets_kernel(const int* __restrict__ bcnt, int* __restrict__ bbase,
                                    int* __restrict__ cursor, int* __restrict__ row_ptr,
                                    int nbuck, int N, int E) {
    __shared__ int lds[1024];
    int T = threadIdx.x;
    int s = (T < nbuck) ? bcnt[T * PAD] : 0;
    lds[T] = s;
    __syncthreads();
    for (int off = 1; off < 1024; off <<= 1) {
        int v = (T >= off) ? lds[T - off] : 0;
        __syncthreads();
        lds[T] += v;
        __syncthreads();
    }
    int excl = lds[T] - s;
    if (T < nbuck) { bbase[T] = excl; cursor[T * PAD] = excl; }
    if (T == 0)    { bbase[nbuck] = E; row_ptr[N] = E; }
}

// scatter edges into bucket-grouped records; per-edge offsets via LDS cursors,
// ~nbuck global atomics per block.  record = {row | dst_local<<17, ew}
__global__ void scatter_kernel(const int* __restrict__ row, const int* __restrict__ col,
                               const float* __restrict__ ew, int* __restrict__ cursor,
                               uint2* __restrict__ part, int nbuck, int E) {
    __shared__ int lcnt[MAXBUCK];
    __shared__ int lbase[MAXBUCK];
    int tid = threadIdx.x;
    for (int i = tid; i < nbuck; i += blockDim.x) lcnt[i] = 0;
    __syncthreads();
    int base = blockIdx.x * CH;
    int end  = min(E, base + CH);
    for (int e = base + tid; e < end; e += blockDim.x)
        atomicAdd(&lcnt[col[e] >> RSHIFT], 1);
    __syncthreads();
    for (int i = tid; i < nbuck; i += blockDim.x) {
        int c = lcnt[i];
        lbase[i] = c ? atomicAdd(&cursor[i * PAD], c) : 0;
        lcnt[i] = 0;
    }
    __syncthreads();
    for (int e = base + tid; e < end; e += blockDim.x) {
        int c = col[e];
        int b = c >> RSHIFT;
        int off = atomicAdd(&lcnt[b], 1);
        part[lbase[b] + off] =
            make_uint2((unsigned)row[e] | ((unsigned)(c & (RANGE - 1)) << 17),
                       __float_as_uint(ew[e]));
    }
}

// one block per bucket: exact per-node CSR + row_ptr + dis, all in LDS
__global__ void bucket_csr_kernel(const uint2* __restrict__ part, const int* __restrict__ bbase,
                                  int* __restrict__ row_ptr, float* __restrict__ dis,
                                  uint2* __restrict__ csr, int N) {
    __shared__ int   scnt[RANGE];
    __shared__ float sdeg[RANGE];
    __shared__ int   sscan[RANGE];
    int b = blockIdx.x;
    int tid = threadIdx.x;
    int s = bbase[b], t = bbase[b + 1];
    if (tid < RANGE) { scnt[tid] = 0; sdeg[tid] = 1.0f; }  // deg starts at self-loop weight
    __syncthreads();
    for (int e = s + tid; e < t; e += blockDim.x) {
        uint2 r = part[e];
        int c = (r.x >> 17) & (RANGE - 1);
        atomicAdd(&scnt[c], 1);
        atomicAdd(&sdeg[c], __uint_as_float(r.y));
    }
    __syncthreads();
    int cnt_t = 0;
    if (tid < RANGE) { cnt_t = scnt[tid]; sscan[tid] = cnt_t; }
    __syncthreads();
    for (int off = 1; off < RANGE; off <<= 1) {
        int v = 0;
        if (tid < RANGE && tid >= off) v = sscan[tid - off];
        __syncthreads();
        if (tid < RANGE) sscan[tid] += v;
        __syncthreads();
    }
    if (tid < RANGE) {
        int excl = sscan[tid] - cnt_t;
        int node = b * RANGE + tid;
        if (node < N) {
            row_ptr[node] = s + excl;
            dis[node] = rsqrtf(sdeg[tid]);
        }
        scnt[tid] = excl;  // reuse as within-bucket cursor
    }
    __syncthreads();
    for (int e = s + tid; e < t; e += blockDim.x) {
        uint2 r = part[e];
        int c = (r.x >> 17) & (RANGE - 1);
        int off = atomicAdd(&scnt[c], 1);
        csr[s + off] = make_uint2(r.x & 0x1FFFFu, r.y);
    }
}

// t1 = X @ W1   ([N,128] @ [128,12], row stride 16 -> one 64B line per node);
// one wave per node
__global__ void lin1_kernel(const float* __restrict__ X, const float* __restrict__ W1,
                            float* __restrict__ t1, int n) {
    int node = (int)((blockIdx.x * (size_t)blockDim.x + threadIdx.x) >> 6);
    int lane = threadIdx.x & 63;
    if (node >= n) return;
    const float* xr = X + (size_t)node * 128;
    float x0 = xr[lane];
    float x1 = xr[lane + 64];
    float res[12];
#pragma unroll
    for (int o = 0; o < 12; o++) {
        float p = x0 * W1[lane * 12 + o] + x1 * W1[(lane + 64) * 12 + o];
#pragma unroll
        for (int off = 32; off > 0; off >>= 1) p += __shfl_xor(p, off, 64);
        res[o] = p;
    }
    if (lane == 0) {
        float4* o4 = (float4*)(t1 + (size_t)node * 16);
        o4[0] = make_float4(res[0], res[1], res[2], res[3]);
        o4[1] = make_float4(res[4], res[5], res[6], res[7]);
        o4[2] = make_float4(res[8], res[9], res[10], res[11]);
    }
}

// Pull aggregation, 8 lanes per destination node: coalesced 64B CSR line per
// group, 800K threads (high occupancy + MLP), 3-step shuffle reduction.
template <int DIN, int SIN, int DOUT, int SOUT, bool FIRST, bool LAST>
__global__ void agg_kernel(const int* __restrict__ row_ptr, uint2* __restrict__ csr,
                           const float* __restrict__ dis, const float* __restrict__ hin,
                           const float* __restrict__ b_this, const float* __restrict__ W_next,
                           const float* __restrict__ b_next, float* __restrict__ hout, int n) {
    int gt   = blockIdx.x * blockDim.x + threadIdx.x;
    int node = gt >> 3;
    int sub  = gt & 7;
    if (node >= n) return;
    int start = row_ptr[node];
    int end   = row_ptr[node + 1];
    float dn  = dis[node];
    float acc[DIN];
#pragma unroll
    for (int d = 0; d < DIN; d++) acc[d] = 0.f;

    for (int e = start + sub; e < end; e += 8) {
        uint2 ev = csr[e];
        int r = (int)ev.x;
        float norm;
        if constexpr (FIRST) {
            norm = dn * __uint_as_float(ev.y) * dis[r];
            csr[e].y = __float_as_uint(norm);
        } else {
            norm = __uint_as_float(ev.y);
        }
        const float* hr = hin + (size_t)r * SIN;
        if constexpr (DIN == 12) {
            const float4* p = (const float4*)hr;
            float4 a = p[0], b = p[1], c = p[2];
            acc[0] += norm * a.x;  acc[1] += norm * a.y;  acc[2]  += norm * a.z;  acc[3]  += norm * a.w;
            acc[4] += norm * b.x;  acc[5] += norm * b.y;  acc[6]  += norm * b.z;  acc[7]  += norm * b.w;
            acc[8] += norm * c.x;  acc[9] += norm * c.y;  acc[10] += norm * c.z;  acc[11] += norm * c.w;
        } else if constexpr (DIN == 6) {
            float4 a = *(const float4*)hr;
            float2 b = *(const float2*)(hr + 4);
            acc[0] += norm * a.x;  acc[1] += norm * a.y;  acc[2] += norm * a.z;
            acc[3] += norm * a.w;  acc[4] += norm * b.x;  acc[5] += norm * b.y;
        } else {  // DIN == 3
            float4 a = *(const float4*)hr;
            acc[0] += norm * a.x;  acc[1] += norm * a.y;  acc[2] += norm * a.z;
        }
    }

#pragma unroll
    for (int d = 0; d < DIN; d++) {
        acc[d] += __shfl_xor(acc[d], 1, 64);
        acc[d] += __shfl_xor(acc[d], 2, 64);
        acc[d] += __shfl_xor(acc[d], 4, 64);
    }

    if (sub == 0) {
        float s2 = dn * dn;
        const float* hn = hin + (size_t)node * SIN;
        float v[DIN];
#pragma unroll
        for (int d = 0; d < DIN; d++)
            v[d] = fmaxf(acc[d] + s2 * hn[d] + b_this[d], 0.f);
        if constexpr (!LAST) {
            float o[DOUT];
#pragma unroll
            for (int oo = 0; oo < DOUT; oo++) {
                float s = 0.f;
#pragma unroll
                for (int d = 0; d < DIN; d++) s += v[d] * W_next[d * DOUT + oo];
                o[oo] = s;
            }
            float* op = hout + (size_t)node * SOUT;
            if constexpr (DOUT == 6) {
                *(float4*)op       = make_float4(o[0], o[1], o[2], o[3]);
                *(float4*)(op + 4) = make_float4(o[4], o[5], 0.f, 0.f);
            } else {  // DOUT == 3, SOUT == 4
                *(float4*)op = make_float4(o[0], o[1], o[2], 0.f);
            }
        } else {
            float z = b_next[0];
#pragma unroll
            for (int d = 0; d < DIN; d++) z += v[d] * W_next[d];
            hout[node] = 1.0f / (1.0f + expf(-z));
        }
    }
}

// ---------------------------------------------------------------------------
extern "C" void kernel_launch(void* const* d_in, const int* in_sizes, int n_in,
                              void* d_out, int out_size, void* d_ws, size_t ws_size,
                              hipStream_t stream) {
    const float* X  = (const float*)d_in[0];
    const int*   ei = (const int*)d_in[1];
    const float* ew = (const float*)d_in[2];
    const float* W1 = (const float*)d_in[3];
    const float* b1 = (const float*)d_in[4];
    const float* W2 = (const float*)d_in[5];
    const float* b2 = (const float*)d_in[6];
    const float* W3 = (const float*)d_in[7];
    const float* b3 = (const float*)d_in[8];
    const float* Wl = (const float*)d_in[9];
    const float* bl = (const float*)d_in[10];
    float* out = (float*)d_out;

    const int N = in_sizes[0] / 128;
    const int E = in_sizes[1] / 2;
    const int* row = ei;
    const int* col = ei + E;
    const int nbuck = (N + RANGE - 1) >> RSHIFT;

    char* ws = (char*)d_ws;
    size_t off = 0;
    auto carve = [&](size_t bytes) -> void* {
        void* p = ws + off;
        off += (bytes + 255) & ~(size_t)255;
        return p;
    };
    int*   bcnt    = (int*)  carve((size_t)MAXBUCK * PAD * 4);
    int*   cursor  = (int*)  carve((size_t)MAXBUCK * PAD * 4);
    int*   bbase   = (int*)  carve((size_t)(MAXBUCK + 1) * 4);
    int*   row_ptr = (int*)  carve((size_t)(N + 1) * 4);
    float* dis     = (float*)carve((size_t)N * 4);
    uint2* part    = (uint2*)carve((size_t)E * 8);
    uint2* csr     = (uint2*)carve((size_t)E * 8);
    // t1/t2/t3 alias `part` (dead after bucket_csr_kernel; stream order keeps this safe)
    float* t1 = (float*)part;
    float* t2 = t1 + (size_t)N * 16;
    float* t3 = t2 + (size_t)N * 8;
    (void)ws_size; (void)n_in; (void)out_size;

    const int bP = (E + CH - 1) / CH;              // 1563 partition blocks
    const int bW = (N + 3) / 4;                    // lin1: wave per node
    const int bA = ((size_t)N * 8 + 255) / 256;    // agg: 8 lanes per node

    zero_pad_kernel<<<(nbuck + 255) / 256, 256, 0, stream>>>(bcnt, nbuck);
    count_kernel<<<bP, 256, 0, stream>>>(col, bcnt, nbuck, E);
    scan_buckets_kernel<<<1, 1024, 0, stream>>>(bcnt, bbase, cursor, row_ptr, nbuck, N, E);
    scatter_kernel<<<bP, 256, 0, stream>>>(row, col, ew, cursor, part, nbuck, E);
    bucket_csr_kernel<<<nbuck, 256, 0, stream>>>(part, bbase, row_ptr, dis, csr, N);
    lin1_kernel<<<bW, 256, 0, stream>>>(X, W1, t1, N);
    agg_kernel<12, 16, 6, 8, true,  false><<<bA, 256, 0, stream>>>(row_ptr, csr, dis, t1, b1, W2, nullptr, t2, N);
    agg_kernel< 6,  8, 3, 4, false, false><<<bA, 256, 0, stream>>>(row_ptr, csr, dis, t2, b2, W3, nullptr, t3, N);
    agg_kernel< 3,  4, 1, 1, false, true ><<<bA, 256, 0, stream>>>(row_ptr, csr, dis, t3, b3, Wl, bl, out, N);
}

// Round 6
// 637.517 us; speedup vs baseline: 2.2771x; 1.2276x over previous
//
#include <hip/hip_runtime.h>
#include <cstdint>
#include <cstddef>

#define RANGE    128       // nodes per fine bucket
#define RSHIFT   7
#define MAXBUCK  800       // >= ceil(N/RANGE); N=100K -> 782
#define CSHIFT   12        // nodes per coarse bucket = 4096
#define CRANGE   4096
#define MAXC     32        // >= ceil(N/CRANGE); N=100K -> 25
#define FPB      32        // fine buckets per coarse bucket (CRANGE/RANGE)
#define CH_CNT   16384     // edges per block, count pass
#define CH_SC    4096      // edges per block, scatter passes
#define PAD      16        // pad global counters to one 64B line each

// ---------------------------------------------------------------------------
__global__ void zero_pad_kernel(int* __restrict__ p, int n) {
    int i = blockIdx.x * blockDim.x + threadIdx.x;
    if (i < n) p[i * PAD] = 0;
}

// fine histogram (782 buckets) of col>>7; per-block LDS, merged w/ global atomics
__global__ void count_kernel(const int* __restrict__ col, int* __restrict__ fcnt,
                             int nfine, int E) {
    __shared__ int lcnt[MAXBUCK];
    int tid = threadIdx.x;
    for (int i = tid; i < nfine; i += blockDim.x) lcnt[i] = 0;
    __syncthreads();
    int base = blockIdx.x * CH_CNT;
    int end  = min(E, base + CH_CNT);
    for (int e = base + tid; e < end; e += blockDim.x)
        atomicAdd(&lcnt[col[e] >> RSHIFT], 1);
    __syncthreads();
    for (int i = tid; i < nfine; i += blockDim.x)
        if (lcnt[i]) atomicAdd(&fcnt[i * PAD], lcnt[i]);
}

// scan fine counts -> fine bases/cursors; derive coarse bases/cursors
__global__ void scan_kernel(const int* __restrict__ fcnt, int* __restrict__ fbase,
                            int* __restrict__ fcur, int* __restrict__ cbase,
                            int* __restrict__ ccur, int* __restrict__ row_ptr,
                            int nfine, int ncoarse, int N, int E) {
    __shared__ int lds[1024];
    int T = threadIdx.x;
    int s = (T < nfine) ? fcnt[T * PAD] : 0;
    lds[T] = s;
    __syncthreads();
    for (int off = 1; off < 1024; off <<= 1) {
        int v = (T >= off) ? lds[T - off] : 0;
        __syncthreads();
        lds[T] += v;
        __syncthreads();
    }
    int excl = lds[T] - s;
    if (T < nfine) { fbase[T] = excl; fcur[T * PAD] = excl; }
    if ((T & (FPB - 1)) == 0 && (T >> 5) < ncoarse) {
        cbase[T >> 5] = excl;
        ccur[(T >> 5) * PAD] = excl;
    }
    if (T == 0) { fbase[nfine] = E; cbase[ncoarse] = E; row_ptr[N] = E; }
}

// coarse scatter: 25 buckets (col>>12) -> partA.  record = {row | col_low12<<17, ew}
// per-block segments ~164 edges => full-line writes
__global__ void coarse_scatter_kernel(const int* __restrict__ row, const int* __restrict__ col,
                                      const float* __restrict__ ew, int* __restrict__ ccur,
                                      uint2* __restrict__ partA, int ncoarse, int E) {
    __shared__ int lcnt[MAXC];
    __shared__ int lbase[MAXC];
    int tid = threadIdx.x;
    if (tid < MAXC) lcnt[tid] = 0;
    __syncthreads();
    int base = blockIdx.x * CH_SC;
    int end  = min(E, base + CH_SC);
    for (int e = base + tid; e < end; e += blockDim.x)
        atomicAdd(&lcnt[col[e] >> CSHIFT], 1);
    __syncthreads();
    if (tid < ncoarse) {
        int c = lcnt[tid];
        lbase[tid] = c ? atomicAdd(&ccur[tid * PAD], c) : 0;
        lcnt[tid] = 0;
    }
    __syncthreads();
    for (int e = base + tid; e < end; e += blockDim.x) {
        int c = col[e];
        int b = c >> CSHIFT;
        int off = atomicAdd(&lcnt[b], 1);
        partA[lbase[b] + off] =
            make_uint2((unsigned)row[e] | ((unsigned)(c & (CRANGE - 1)) << 17),
                       __float_as_uint(ew[e]));
    }
}

// fine scatter: partA (coarsely sorted) -> partB grouped by 128-node fine bucket.
// each chunk spans ~33 fine buckets => ~128-edge segments => full-line writes.
// output record = {row | dst_local<<17, ew}  (same format downstream as before)
__global__ void fine_scatter_kernel(const uint2* __restrict__ partA, const int* __restrict__ cbase,
                                    int* __restrict__ fcur, uint2* __restrict__ partB,
                                    int nfine, int ncoarse, int E) {
    __shared__ int lcnt[MAXBUCK];
    __shared__ int lbase[MAXBUCK];
    __shared__ int scb[MAXC + 1];
    __shared__ int rlo_s;
    int tid = threadIdx.x;
    int base = blockIdx.x * CH_SC;
    int end  = min(E, base + CH_SC);
    if (tid <= ncoarse) scb[tid] = cbase[tid];
    for (int i = tid; i < nfine; i += blockDim.x) lcnt[i] = 0;
    if (tid == 0) {
        int r = 0;
        while (r < ncoarse - 1 && cbase[r + 1] <= base) ++r;
        rlo_s = r;
    }
    __syncthreads();
    int rlo = rlo_s;
    for (int e = base + tid; e < end; e += blockDim.x) {
        int r = rlo;
        while (e >= scb[r + 1]) ++r;
        int col12 = (int)((partA[e].x >> 17) & (CRANGE - 1));
        atomicAdd(&lcnt[(r << 5) | (col12 >> RSHIFT)], 1);
    }
    __syncthreads();
    for (int i = tid; i < nfine; i += blockDim.x) {
        int c = lcnt[i];
        lbase[i] = c ? atomicAdd(&fcur[i * PAD], c) : 0;
        lcnt[i] = 0;
    }
    __syncthreads();
    for (int e = base + tid; e < end; e += blockDim.x) {
        uint2 v = partA[e];
        int r = rlo;
        while (e >= scb[r + 1]) ++r;
        int col12 = (int)((v.x >> 17) & (CRANGE - 1));
        int f = (r << 5) | (col12 >> RSHIFT);
        int off = atomicAdd(&lcnt[f], 1);
        partB[lbase[f] + off] =
            make_uint2((v.x & 0x1FFFFu) | ((unsigned)(col12 & (RANGE - 1)) << 17), v.y);
    }
}

// one block per fine bucket: exact per-node CSR + row_ptr + dis, all in LDS
__global__ void bucket_csr_kernel(const uint2* __restrict__ part, const int* __restrict__ bbase,
                                  int* __restrict__ row_ptr, float* __restrict__ dis,
                                  uint2* __restrict__ csr, int N) {
    __shared__ int   scnt[RANGE];
    __shared__ float sdeg[RANGE];
    __shared__ int   sscan[RANGE];
    int b = blockIdx.x;
    int tid = threadIdx.x;
    int s = bbase[b], t = bbase[b + 1];
    if (tid < RANGE) { scnt[tid] = 0; sdeg[tid] = 1.0f; }  // deg starts at self-loop weight
    __syncthreads();
    for (int e = s + tid; e < t; e += blockDim.x) {
        uint2 r = part[e];
        int c = (r.x >> 17) & (RANGE - 1);
        atomicAdd(&scnt[c], 1);
        atomicAdd(&sdeg[c], __uint_as_float(r.y));
    }
    __syncthreads();
    int cnt_t = 0;
    if (tid < RANGE) { cnt_t = scnt[tid]; sscan[tid] = cnt_t; }
    __syncthreads();
    for (int off = 1; off < RANGE; off <<= 1) {
        int v = 0;
        if (tid < RANGE && tid >= off) v = sscan[tid - off];
        __syncthreads();
        if (tid < RANGE) sscan[tid] += v;
        __syncthreads();
    }
    if (tid < RANGE) {
        int excl = sscan[tid] - cnt_t;
        int node = b * RANGE + tid;
        if (node < N) {
            row_ptr[node] = s + excl;
            dis[node] = rsqrtf(sdeg[tid]);
        }
        scnt[tid] = excl;  // reuse as within-bucket cursor
    }
    __syncthreads();
    for (int e = s + tid; e < t; e += blockDim.x) {
        uint2 r = part[e];
        int c = (r.x >> 17) & (RANGE - 1);
        int off = atomicAdd(&scnt[c], 1);
        csr[s + off] = make_uint2(r.x & 0x1FFFFu, r.y);
    }
}

// t1 = X @ W1   ([N,128] @ [128,12], row stride 16 -> one 64B line per node);
// one wave per node
__global__ void lin1_kernel(const float* __restrict__ X, const float* __restrict__ W1,
                            float* __restrict__ t1, int n) {
    int node = (int)((blockIdx.x * (size_t)blockDim.x + threadIdx.x) >> 6);
    int lane = threadIdx.x & 63;
    if (node >= n) return;
    const float* xr = X + (size_t)node * 128;
    float x0 = xr[lane];
    float x1 = xr[lane + 64];
    float res[12];
#pragma unroll
    for (int o = 0; o < 12; o++) {
        float p = x0 * W1[lane * 12 + o] + x1 * W1[(lane + 64) * 12 + o];
#pragma unroll
        for (int off = 32; off > 0; off >>= 1) p += __shfl_xor(p, off, 64);
        res[o] = p;
    }
    if (lane == 0) {
        float4* o4 = (float4*)(t1 + (size_t)node * 16);
        o4[0] = make_float4(res[0], res[1], res[2], res[3]);
        o4[1] = make_float4(res[4], res[5], res[6], res[7]);
        o4[2] = make_float4(res[8], res[9], res[10], res[11]);
    }
}

// Pull aggregation, 8 lanes per destination node: coalesced 64B CSR line per
// group, 800K threads (high occupancy + MLP), 3-step shuffle reduction.
template <int DIN, int SIN, int DOUT, int SOUT, bool FIRST, bool LAST>
__global__ void agg_kernel(const int* __restrict__ row_ptr, uint2* __restrict__ csr,
                           const float* __restrict__ dis, const float* __restrict__ hin,
                           const float* __restrict__ b_this, const float* __restrict__ W_next,
                           const float* __restrict__ b_next, float* __restrict__ hout, int n) {
    int gt   = blockIdx.x * blockDim.x + threadIdx.x;
    int node = gt >> 3;
    int sub  = gt & 7;
    if (node >= n) return;
    int start = row_ptr[node];
    int end   = row_ptr[node + 1];
    float dn  = dis[node];
    float acc[DIN];
#pragma unroll
    for (int d = 0; d < DIN; d++) acc[d] = 0.f;

    for (int e = start + sub; e < end; e += 8) {
        uint2 ev = csr[e];
        int r = (int)ev.x;
        float norm;
        if constexpr (FIRST) {
            norm = dn * __uint_as_float(ev.y) * dis[r];
            csr[e].y = __float_as_uint(norm);
        } else {
            norm = __uint_as_float(ev.y);
        }
        const float* hr = hin + (size_t)r * SIN;
        if constexpr (DIN == 12) {
            const float4* p = (const float4*)hr;
            float4 a = p[0], b = p[1], c = p[2];
            acc[0] += norm * a.x;  acc[1] += norm * a.y;  acc[2]  += norm * a.z;  acc[3]  += norm * a.w;
            acc[4] += norm * b.x;  acc[5] += norm * b.y;  acc[6]  += norm * b.z;  acc[7]  += norm * b.w;
            acc[8] += norm * c.x;  acc[9] += norm * c.y;  acc[10] += norm * c.z;  acc[11] += norm * c.w;
        } else if constexpr (DIN == 6) {
            float4 a = *(const float4*)hr;
            float2 b = *(const float2*)(hr + 4);
            acc[0] += norm * a.x;  acc[1] += norm * a.y;  acc[2] += norm * a.z;
            acc[3] += norm * a.w;  acc[4] += norm * b.x;  acc[5] += norm * b.y;
        } else {  // DIN == 3
            float4 a = *(const float4*)hr;
            acc[0] += norm * a.x;  acc[1] += norm * a.y;  acc[2] += norm * a.z;
        }
    }

#pragma unroll
    for (int d = 0; d < DIN; d++) {
        acc[d] += __shfl_xor(acc[d], 1, 64);
        acc[d] += __shfl_xor(acc[d], 2, 64);
        acc[d] += __shfl_xor(acc[d], 4, 64);
    }

    if (sub == 0) {
        float s2 = dn * dn;
        const float* hn = hin + (size_t)node * SIN;
        float v[DIN];
#pragma unroll
        for (int d = 0; d < DIN; d++)
            v[d] = fmaxf(acc[d] + s2 * hn[d] + b_this[d], 0.f);
        if constexpr (!LAST) {
            float o[DOUT];
#pragma unroll
            for (int oo = 0; oo < DOUT; oo++) {
                float s = 0.f;
#pragma unroll
                for (int d = 0; d < DIN; d++) s += v[d] * W_next[d * DOUT + oo];
                o[oo] = s;
            }
            float* op = hout + (size_t)node * SOUT;
            if constexpr (DOUT == 6) {
                *(float4*)op       = make_float4(o[0], o[1], o[2], o[3]);
                *(float4*)(op + 4) = make_float4(o[4], o[5], 0.f, 0.f);
            } else {  // DOUT == 3, SOUT == 4
                *(float4*)op = make_float4(o[0], o[1], o[2], 0.f);
            }
        } else {
            float z = b_next[0];
#pragma unroll
            for (int d = 0; d < DIN; d++) z += v[d] * W_next[d];
            hout[node] = 1.0f / (1.0f + expf(-z));
        }
    }
}

// ---------------------------------------------------------------------------
extern "C" void kernel_launch(void* const* d_in, const int* in_sizes, int n_in,
                              void* d_out, int out_size, void* d_ws, size_t ws_size,
                              hipStream_t stream) {
    const float* X  = (const float*)d_in[0];
    const int*   ei = (const int*)d_in[1];
    const float* ew = (const float*)d_in[2];
    const float* W1 = (const float*)d_in[3];
    const float* b1 = (const float*)d_in[4];
    const float* W2 = (const float*)d_in[5];
    const float* b2 = (const float*)d_in[6];
    const float* W3 = (const float*)d_in[7];
    const float* b3 = (const float*)d_in[8];
    const float* Wl = (const float*)d_in[9];
    const float* bl = (const float*)d_in[10];
    float* out = (float*)d_out;

    const int N = in_sizes[0] / 128;
    const int E = in_sizes[1] / 2;
    const int* row = ei;
    const int* col = ei + E;
    const int nfine   = (N + RANGE - 1) >> RSHIFT;
    const int ncoarse = (N + CRANGE - 1) >> CSHIFT;

    char* ws = (char*)d_ws;
    size_t off = 0;
    auto carve = [&](size_t bytes) -> void* {
        void* p = ws + off;
        off += (bytes + 255) & ~(size_t)255;
        return p;
    };
    int*   fcnt    = (int*)  carve((size_t)MAXBUCK * PAD * 4);
    int*   fcur    = (int*)  carve((size_t)MAXBUCK * PAD * 4);
    int*   ccur    = (int*)  carve((size_t)MAXC * PAD * 4);
    int*   cbase   = (int*)  carve((size_t)(MAXC + 1) * 4);
    int*   fbase   = (int*)  carve((size_t)(MAXBUCK + 1) * 4);
    int*   row_ptr = (int*)  carve((size_t)(N + 1) * 4);
    float* dis     = (float*)carve((size_t)N * 4);
    uint2* partA   = (uint2*)carve((size_t)E * 8);
    uint2* partB   = (uint2*)carve((size_t)E * 8);
    // csr reuses partA (dead after fine scatter); t1/t2/t3 reuse partB (dead after bucket_csr)
    uint2* csr = partA;
    float* t1  = (float*)partB;
    float* t2  = t1 + (size_t)N * 16;
    float* t3  = t2 + (size_t)N * 8;
    (void)ws_size; (void)n_in; (void)out_size;

    const int bCnt = (E + CH_CNT - 1) / CH_CNT;    // 391 count blocks
    const int bSc  = (E + CH_SC - 1) / CH_SC;      // 1563 scatter blocks
    const int bW   = (N + 3) / 4;                  // lin1: wave per node
    const int bA   = ((size_t)N * 8 + 255) / 256;  // agg: 8 lanes per node

    zero_pad_kernel<<<(nfine + 255) / 256, 256, 0, stream>>>(fcnt, nfine);
    count_kernel<<<bCnt, 256, 0, stream>>>(col, fcnt, nfine, E);
    scan_kernel<<<1, 1024, 0, stream>>>(fcnt, fbase, fcur, cbase, ccur, row_ptr,
                                        nfine, ncoarse, N, E);
    coarse_scatter_kernel<<<bSc, 256, 0, stream>>>(row, col, ew, ccur, partA, ncoarse, E);
    fine_scatter_kernel<<<bSc, 256, 0, stream>>>(partA, cbase, fcur, partB, nfine, ncoarse, E);
    bucket_csr_kernel<<<nfine, 256, 0, stream>>>(partB, fbase, row_ptr, dis, csr, N);
    lin1_kernel<<<bW, 256, 0, stream>>>(X, W1, t1, N);
    agg_kernel<12, 16, 6, 8, true,  false><<<bA, 256, 0, stream>>>(row_ptr, csr, dis, t1, b1, W2, nullptr, t2, N);
    agg_kernel< 6,  8, 3, 4, false, false><<<bA, 256, 0, stream>>>(row_ptr, csr, dis, t2, b2, W3, nullptr, t3, N);
    agg_kernel< 3,  4, 1, 1, false, true ><<<bA, 256, 0, stream>>>(row_ptr, csr, dis, t3, b3, Wl, bl, out, N);
}